// Round 3
// baseline (241.609 us; speedup 1.0000x reference)
//
#include <hip/hip_runtime.h>

typedef _Float16 half_t;
typedef _Float16 half2_t __attribute__((ext_vector_type(2)));
typedef _Float16 half4_t __attribute__((ext_vector_type(4)));
typedef _Float16 half8 __attribute__((ext_vector_type(8)));
typedef float f32x4 __attribute__((ext_vector_type(4)));
typedef float f32x16 __attribute__((ext_vector_type(16)));
typedef unsigned uint4v __attribute__((ext_vector_type(4)));

__device__ __forceinline__ void gload_lds16(const void* g, void* l) {
    __builtin_amdgcn_global_load_lds(
        (const __attribute__((address_space(1))) void*)g,
        (__attribute__((address_space(3))) void*)l, 16, 0, 0);
}

// ---------------- cast fp32 -> fp16 (vectorized, grid-stride) ----------------
__global__ __launch_bounds__(256) void cast_f32_f16(const float* __restrict__ s,
                                                    half_t* __restrict__ d, int n) {
    const int stride = gridDim.x * blockDim.x;
    for (int i = blockIdx.x * blockDim.x + threadIdx.x; i * 4 < n; i += stride) {
        const float4 v = *(const float4*)(s + (long)i * 4);
        half4_t h = {(half_t)v.x, (half_t)v.y, (half_t)v.z, (half_t)v.w};
        *(half4_t*)(d + (long)i * 4) = h;
    }
}

__global__ __launch_bounds__(256) void concat_bias(const float* __restrict__ a,
                                                   const float* __restrict__ b,
                                                   const float* __restrict__ c,
                                                   float* __restrict__ o) {
    int i = blockIdx.x * blockDim.x + threadIdx.x;
    if (i < 768) o[i] = a[i];
    else if (i < 1536) o[i] = b[i - 768];
    else if (i < 2304) o[i] = c[i - 1536];
}

// ---------------- GEMM: C[M,N] = A[M,K] * W[N,K]^T + bias[N] ----------------
template <typename OutT>
__global__ __launch_bounds__(256) void gemm_bt(const half_t* __restrict__ A,
                                               const half_t* __restrict__ W,
                                               const float* __restrict__ bias,
                                               OutT* __restrict__ C,
                                               int M, int N, int K) {
    alignas(16) __shared__ half_t Ah[128 * 32];
    alignas(16) __shared__ half_t Wh[128 * 32];
    const int t = threadIdx.x;
    const int l = t & 63, w = t >> 6;
    const int m0 = blockIdx.x * 128, n0 = blockIdx.y * 128;
    const int wr = w >> 1, wc = w & 1;

    f32x4 acc[4][4] = {};

    const int srow = w * 16 + (l >> 2);
    const int scol = (l & 3) * 8;
    const half_t* Ag = A + (long)(m0 + srow) * K + scol;
    const half_t* Wg = W + (long)(n0 + srow) * K + scol;
    half_t* lA0 = &Ah[(w * 16) * 32];
    half_t* lA1 = &Ah[(w * 16 + 64) * 32];
    half_t* lW0 = &Wh[(w * 16) * 32];
    half_t* lW1 = &Wh[(w * 16 + 64) * 32];

    for (int k0 = 0; k0 < K; k0 += 32) {
        gload_lds16(Ag + k0, lA0);
        gload_lds16(Ag + (long)64 * K + k0, lA1);
        gload_lds16(Wg + k0, lW0);
        gload_lds16(Wg + (long)64 * K + k0, lW1);
        __syncthreads();

        half8 af[4], bf[4];
        const int ak = (l >> 4) * 8;
#pragma unroll
        for (int m = 0; m < 4; ++m)
            af[m] = *(const half8*)&Ah[(wr * 64 + m * 16 + (l & 15)) * 32 + ak];
#pragma unroll
        for (int n = 0; n < 4; ++n)
            bf[n] = *(const half8*)&Wh[(wc * 64 + n * 16 + (l & 15)) * 32 + ak];
#pragma unroll
        for (int m = 0; m < 4; ++m)
#pragma unroll
            for (int n = 0; n < 4; ++n)
                acc[m][n] = __builtin_amdgcn_mfma_f32_16x16x32_f16(af[m], bf[n], acc[m][n], 0, 0, 0);
        __syncthreads();
    }

#pragma unroll
    for (int m = 0; m < 4; ++m) {
        const int row = m0 + wr * 64 + m * 16 + (l >> 4) * 4;
#pragma unroll
        for (int n = 0; n < 4; ++n) {
            const int col = n0 + wc * 64 + n * 16 + (l & 15);
            const float bb = bias ? bias[col] : 0.f;
#pragma unroll
            for (int r = 0; r < 4; ++r) {
                float v = acc[m][n][r] + bb;
                C[(long)(row + r) * N + col] = (OutT)v;
            }
        }
    }
}

// ---------------- V transpose: qkv V-part -> Vt[bh][d=64][n=1024] ----------------
__global__ __launch_bounds__(256) void transpose_v(const half_t* __restrict__ qkv,
                                                   half_t* __restrict__ Vt) {
    __shared__ half_t Ld[64][68];
    const int bh = blockIdx.y;
    const int n0 = blockIdx.x * 64;
    const int b = bh / 12, h = bh % 12;
    const int t = threadIdx.x;
#pragma unroll
    for (int rr = 0; rr < 2; ++rr) {
        const int row = rr * 32 + (t >> 3);
        const half_t* src = qkv + ((long)(b * 1024 + n0 + row)) * 2304 + 1536 + h * 64 + (t & 7) * 8;
        half4_t a = *(const half4_t*)src;
        half4_t c = *(const half4_t*)(src + 4);
        *(half4_t*)&Ld[row][(t & 7) * 8] = a;
        *(half4_t*)&Ld[row][(t & 7) * 8 + 4] = c;
    }
    __syncthreads();
#pragma unroll
    for (int dd = 0; dd < 2; ++dd) {
        const int d = dd * 32 + (t >> 3);
        half8 w;
#pragma unroll
        for (int j = 0; j < 8; ++j) w[j] = Ld[(t & 7) * 8 + j][d];
        *(half8*)(Vt + ((long)(bh * 64 + d)) * 1024 + n0 + (t & 7) * 8) = w;
    }
}

// ---------------- flash attention, swapped-operand 32x32 MFMA, no LDS ----------------
// grid (8, 96), block 256 = 4 independent waves; each wave: 32 q-rows, full KV sweep.
// S^T = mfma(K, Q): lane owns q = lane&31 -> per-lane scalar softmax state.
// O^T = mfma(V^T, P): accumulator also q-per-lane -> lane-local rescale.
__global__ __launch_bounds__(256) void attn2_kernel(const half_t* __restrict__ qkv,
                                                    const half_t* __restrict__ Vt,
                                                    const float* __restrict__ head_mask,
                                                    half_t* __restrict__ Y) {
    const int t = threadIdx.x, l = t & 63, wv = t >> 6;
    const int h2 = l >> 5, q32 = l & 31;
    const int bh = blockIdx.y, b = bh / 12, hh = bh % 12;
    const int q0 = blockIdx.x * 128 + wv * 32;

    // Q fragments (B-operand): col = q32, k = kd*16 + h2*8 + j; fold in 1/8 scale
    half8 qf[4];
    {
        const half_t* Qp = qkv + ((long)(b * 1024 + q0 + q32)) * 2304 + hh * 64 + h2 * 8;
#pragma unroll
        for (int kd = 0; kd < 4; ++kd) {
            half8 v = *(const half8*)(Qp + kd * 16);
#pragma unroll
            for (int j = 0; j < 8; ++j) v[j] = v[j] * (half_t)0.125f;
            qf[kd] = v;
        }
    }

    const half_t* Kp = qkv + ((long)(b * 1024 + q32)) * 2304 + 768 + hh * 64 + h2 * 8;
    const half_t* Vp = Vt + ((long)(bh * 64 + q32)) * 1024 + h2 * 8;

    f32x16 o0 = {}, o1 = {};
    float m = -1e30f, ll = 0.f;

    // preload K tile 0: A-frag row = kvb*32 + (l&31), k = kd*16 + h2*8 + j
    half8 kf[8];
#pragma unroll
    for (int kvb = 0; kvb < 2; ++kvb)
#pragma unroll
        for (int kd = 0; kd < 4; ++kd)
            kf[kvb * 4 + kd] = *(const half8*)(Kp + ((long)(kvb * 32)) * 2304 + kd * 16);

    for (int tt = 0; tt < 16; ++tt) {
        // V^T fragments for this tile (consumed after softmax; latency hidden)
        half8 vf[8];
#pragma unroll
        for (int db = 0; db < 2; ++db)
#pragma unroll
            for (int kc = 0; kc < 4; ++kc)
                vf[db * 4 + kc] = *(const half8*)(Vp + (long)db * 32 * 1024 + tt * 64 + kc * 16);

        // S^T[kv][q] = K . Qs^T
        f32x16 s0 = {}, s1 = {};
#pragma unroll
        for (int kd = 0; kd < 4; ++kd) {
            s0 = __builtin_amdgcn_mfma_f32_32x32x16_f16(kf[kd], qf[kd], s0, 0, 0, 0);
            s1 = __builtin_amdgcn_mfma_f32_32x32x16_f16(kf[4 + kd], qf[kd], s1, 0, 0, 0);
        }

        // prefetch next K tile (K regs free after the QK mfmas issue)
        const int tn = tt < 15 ? tt + 1 : 15;
#pragma unroll
        for (int kvb = 0; kvb < 2; ++kvb)
#pragma unroll
            for (int kd = 0; kd < 4; ++kd)
                kf[kvb * 4 + kd] = *(const half8*)(Kp + ((long)(tn * 64 + kvb * 32)) * 2304 + kd * 16);

        // ---- per-lane softmax (lane owns q = l&31; partner lane l^32 has other 16 kv) ----
        float mx = -1e30f;
#pragma unroll
        for (int i = 0; i < 16; ++i) mx = fmaxf(mx, s0[i]);
#pragma unroll
        for (int i = 0; i < 16; ++i) mx = fmaxf(mx, s1[i]);
        mx = fmaxf(mx, __shfl_xor(mx, 32));

        if (!__all(mx <= m + 8.f)) {          // defer-max (T13)
            const float mn = fmaxf(m, mx);
            const float al = __expf(m - mn);
            m = mn;
            ll *= al;
            o0 *= al;
            o1 *= al;
        }

        // exp + sum + pack pairs (kv runs of 4: kv = b8*32 + rr*8 + 4*h2 + i)
        float sum = 0.f;
        unsigned P2w[8][2];
#pragma unroll
        for (int b8 = 0; b8 < 2; ++b8) {
            const f32x16 ss = b8 ? s1 : s0;
#pragma unroll
            for (int rr = 0; rr < 4; ++rr)
#pragma unroll
                for (int k = 0; k < 2; ++k) {
                    const float a = __expf(ss[rr * 4 + 2 * k] - m);
                    const float c = __expf(ss[rr * 4 + 2 * k + 1] - m);
                    sum += a + c;
                    P2w[b8 * 4 + rr][k] =
                        __builtin_bit_cast(unsigned, __builtin_amdgcn_cvt_pkrtz(a, c));
                }
        }
        sum += __shfl_xor(sum, 32);
        ll += sum;

        // exchange partner's complementary runs: lane needs partner P2[b][2j + h2_own]
        unsigned X[2][2][2];
#pragma unroll
        for (int b8 = 0; b8 < 2; ++b8)
#pragma unroll
            for (int j = 0; j < 2; ++j) {
                const unsigned z0 = h2 ? P2w[b8 * 4 + 2 * j][0] : P2w[b8 * 4 + 2 * j + 1][0];
                const unsigned z1 = h2 ? P2w[b8 * 4 + 2 * j][1] : P2w[b8 * 4 + 2 * j + 1][1];
                X[b8][j][0] = (unsigned)__shfl_xor((int)z0, 32);
                X[b8][j][1] = (unsigned)__shfl_xor((int)z1, 32);
            }

        // P fragment per kv-16 chunk kc; O^T += V^T . P^T
#pragma unroll
        for (int kc = 0; kc < 4; ++kc) {
            const int b8 = kc >> 1, j = kc & 1;
            const unsigned w0 = h2 ? X[b8][j][0] : P2w[b8 * 4 + 2 * j][0];
            const unsigned w1 = h2 ? X[b8][j][1] : P2w[b8 * 4 + 2 * j][1];
            const unsigned w2 = h2 ? P2w[b8 * 4 + 2 * j + 1][0] : X[b8][j][0];
            const unsigned w3 = h2 ? P2w[b8 * 4 + 2 * j + 1][1] : X[b8][j][1];
            uint4v uu = {w0, w1, w2, w3};
            const half8 pf = __builtin_bit_cast(half8, uu);
            o0 = __builtin_amdgcn_mfma_f32_32x32x16_f16(vf[kc], pf, o0, 0, 0, 0);
            o1 = __builtin_amdgcn_mfma_f32_32x32x16_f16(vf[4 + kc], pf, o1, 0, 0, 0);
        }
    }

    // ---- epilogue: lane-local normalize + mask^2; d = db*32 + rq*8 + h2*4 + i ----
    const float hmv = head_mask[b * 12 + hh];
    const float sc = hmv * hmv / ll;
    half_t* Yp = Y + ((long)(b * 1024 + q0 + q32)) * 768 + hh * 64;
#pragma unroll
    for (int db = 0; db < 2; ++db) {
        const f32x16 oo = db ? o1 : o0;
#pragma unroll
        for (int rq = 0; rq < 4; ++rq) {
            half4_t pk;
#pragma unroll
            for (int i = 0; i < 4; ++i) pk[i] = (half_t)(oo[rq * 4 + i] * sc);
            *(half4_t*)(Yp + db * 32 + rq * 8 + h2 * 4) = pk;
        }
    }
}

// ---------------- launch ----------------
extern "C" void kernel_launch(void* const* d_in, const int* in_sizes, int n_in,
                              void* d_out, int out_size, void* d_ws, size_t ws_size,
                              hipStream_t stream) {
    const float* x   = (const float*)d_in[0];
    const float* hm  = (const float*)d_in[1];
    const float* q_w = (const float*)d_in[2];
    const float* q_b = (const float*)d_in[3];
    const float* k_w = (const float*)d_in[4];
    const float* k_b = (const float*)d_in[5];
    const float* v_w = (const float*)d_in[6];
    const float* v_b = (const float*)d_in[7];
    const float* p_w = (const float*)d_in[8];
    const float* p_b = (const float*)d_in[9];
    float* out = (float*)d_out;

    char* ws = (char*)d_ws;
    half_t* xh  = (half_t*)(ws);                    // 8192*768*2   = 12582912
    half_t* wc  = (half_t*)(ws + 12582912);         // 2304*768*2   = 3538944
    half_t* pwh = (half_t*)(ws + 16121856);         // 768*768*2    = 1179648
    float*  bc  = (float*)(ws + 17301504);          // 2304*4       = 9216
    half_t* qkv = (half_t*)(ws + 17310720);         // 8192*2304*2  = 37748736
    half_t* y   = (half_t*)(ws + 55059456);         // 8192*768*2   = 12582912
    half_t* Vt  = xh;                               // reuse xh (dead after QKV GEMM)

    cast_f32_f16<<<2048, 256, 0, stream>>>(x, xh, 8192 * 768);
    cast_f32_f16<<<576, 256, 0, stream>>>(q_w, wc, 768 * 768);
    cast_f32_f16<<<576, 256, 0, stream>>>(k_w, wc + 768 * 768, 768 * 768);
    cast_f32_f16<<<576, 256, 0, stream>>>(v_w, wc + 2 * 768 * 768, 768 * 768);
    cast_f32_f16<<<576, 256, 0, stream>>>(p_w, pwh, 768 * 768);
    concat_bias<<<9, 256, 0, stream>>>(q_b, k_b, v_b, bc);

    gemm_bt<half_t><<<dim3(64, 18), 256, 0, stream>>>(xh, wc, bc, qkv, 8192, 2304, 768);
    transpose_v<<<dim3(16, 96), 256, 0, stream>>>(qkv, Vt);
    attn2_kernel<<<dim3(8, 96), 256, 0, stream>>>(qkv, Vt, hm, y);
    gemm_bt<float><<<dim3(64, 6), 256, 0, stream>>>(y, pwh, p_b, out, 8192, 768, 768);
}

// Round 4
// 166.227 us; speedup vs baseline: 1.4535x; 1.4535x over previous
//
#include <hip/hip_runtime.h>

typedef _Float16 half_t;
typedef _Float16 half2_t __attribute__((ext_vector_type(2)));
typedef _Float16 half4_t __attribute__((ext_vector_type(4)));
typedef _Float16 half8 __attribute__((ext_vector_type(8)));
typedef float f32x4 __attribute__((ext_vector_type(4)));
typedef float f32x16 __attribute__((ext_vector_type(16)));
typedef unsigned uint4v __attribute__((ext_vector_type(4)));

__device__ __forceinline__ void gload_lds16(const void* g, void* l) {
    __builtin_amdgcn_global_load_lds(
        (const __attribute__((address_space(1))) void*)g,
        (__attribute__((address_space(3))) void*)l, 16, 0, 0);
}

// ---------------- cast fp32 -> fp16 (vectorized, grid-stride) ----------------
__global__ __launch_bounds__(256) void cast_f32_f16(const float* __restrict__ s,
                                                    half_t* __restrict__ d, int n) {
    const int stride = gridDim.x * blockDim.x;
    for (int i = blockIdx.x * blockDim.x + threadIdx.x; i * 4 < n; i += stride) {
        const float4 v = *(const float4*)(s + (long)i * 4);
        half4_t h = {(half_t)v.x, (half_t)v.y, (half_t)v.z, (half_t)v.w};
        *(half4_t*)(d + (long)i * 4) = h;
    }
}

__global__ __launch_bounds__(256) void concat_bias(const float* __restrict__ a,
                                                   const float* __restrict__ b,
                                                   const float* __restrict__ c,
                                                   float* __restrict__ o) {
    int i = blockIdx.x * blockDim.x + threadIdx.x;
    if (i < 768) o[i] = a[i];
    else if (i < 1536) o[i] = b[i - 768];
    else if (i < 2304) o[i] = c[i - 1536];
}

// ---------------- GEMM: C[M,N] = A[M,K] * W[N,K]^T + bias[N] ----------------
template <typename OutT>
__global__ __launch_bounds__(256) void gemm_bt(const half_t* __restrict__ A,
                                               const half_t* __restrict__ W,
                                               const float* __restrict__ bias,
                                               OutT* __restrict__ C,
                                               int M, int N, int K) {
    alignas(16) __shared__ half_t Ah[128 * 32];
    alignas(16) __shared__ half_t Wh[128 * 32];
    const int t = threadIdx.x;
    const int l = t & 63, w = t >> 6;
    const int m0 = blockIdx.x * 128, n0 = blockIdx.y * 128;
    const int wr = w >> 1, wc = w & 1;

    f32x4 acc[4][4] = {};

    const int srow = w * 16 + (l >> 2);
    const int scol = (l & 3) * 8;
    const half_t* Ag = A + (long)(m0 + srow) * K + scol;
    const half_t* Wg = W + (long)(n0 + srow) * K + scol;
    half_t* lA0 = &Ah[(w * 16) * 32];
    half_t* lA1 = &Ah[(w * 16 + 64) * 32];
    half_t* lW0 = &Wh[(w * 16) * 32];
    half_t* lW1 = &Wh[(w * 16 + 64) * 32];

    for (int k0 = 0; k0 < K; k0 += 32) {
        gload_lds16(Ag + k0, lA0);
        gload_lds16(Ag + (long)64 * K + k0, lA1);
        gload_lds16(Wg + k0, lW0);
        gload_lds16(Wg + (long)64 * K + k0, lW1);
        __syncthreads();

        half8 af[4], bf[4];
        const int ak = (l >> 4) * 8;
#pragma unroll
        for (int m = 0; m < 4; ++m)
            af[m] = *(const half8*)&Ah[(wr * 64 + m * 16 + (l & 15)) * 32 + ak];
#pragma unroll
        for (int n = 0; n < 4; ++n)
            bf[n] = *(const half8*)&Wh[(wc * 64 + n * 16 + (l & 15)) * 32 + ak];
#pragma unroll
        for (int m = 0; m < 4; ++m)
#pragma unroll
            for (int n = 0; n < 4; ++n)
                acc[m][n] = __builtin_amdgcn_mfma_f32_16x16x32_f16(af[m], bf[n], acc[m][n], 0, 0, 0);
        __syncthreads();
    }

#pragma unroll
    for (int m = 0; m < 4; ++m) {
        const int row = m0 + wr * 64 + m * 16 + (l >> 4) * 4;
#pragma unroll
        for (int n = 0; n < 4; ++n) {
            const int col = n0 + wc * 64 + n * 16 + (l & 15);
            const float bb = bias ? bias[col] : 0.f;
#pragma unroll
            for (int r = 0; r < 4; ++r) {
                float v = acc[m][n][r] + bb;
                C[(long)(row + r) * N + col] = (OutT)v;
            }
        }
    }
}

// ---------------- V transpose: qkv V-part -> Vt[bh][d=64][n=1024] ----------------
__global__ __launch_bounds__(256) void transpose_v(const half_t* __restrict__ qkv,
                                                   half_t* __restrict__ Vt) {
    __shared__ half_t Ld[64][68];
    const int bh = blockIdx.y;
    const int n0 = blockIdx.x * 64;
    const int b = bh / 12, h = bh % 12;
    const int t = threadIdx.x;
#pragma unroll
    for (int rr = 0; rr < 2; ++rr) {
        const int row = rr * 32 + (t >> 3);
        const half_t* src = qkv + ((long)(b * 1024 + n0 + row)) * 2304 + 1536 + h * 64 + (t & 7) * 8;
        half4_t a = *(const half4_t*)src;
        half4_t c = *(const half4_t*)(src + 4);
        *(half4_t*)&Ld[row][(t & 7) * 8] = a;
        *(half4_t*)&Ld[row][(t & 7) * 8 + 4] = c;
    }
    __syncthreads();
#pragma unroll
    for (int dd = 0; dd < 2; ++dd) {
        const int d = dd * 32 + (t >> 3);
        half8 w;
#pragma unroll
        for (int j = 0; j < 8; ++j) w[j] = Ld[(t & 7) * 8 + j][d];
        *(half8*)(Vt + ((long)(bh * 64 + d)) * 1024 + n0 + (t & 7) * 8) = w;
    }
}

// ---------------- flash attention: swapped-operand 32x32 MFMA + LDS-staged K/V ----------------
// grid (8, 96), block 256 = 4 waves; each wave owns 32 q-rows, all share K/V tiles.
// S^T = mfma(K, Q): lane owns q = lane&31 -> per-lane scalar softmax.
// O^T = mfma(V^T, P): accumulator q-per-lane -> lane-local rescale.
// K/V^T staged global->LDS via global_load_lds (coalesced 128B rows, XOR-chunk
// pre-swizzle on source, same XOR on ds_read) with double buffering.
__global__ __launch_bounds__(256) void attn3_kernel(const half_t* __restrict__ qkv,
                                                    const half_t* __restrict__ Vt,
                                                    const float* __restrict__ head_mask,
                                                    half_t* __restrict__ Y) {
    alignas(16) __shared__ half_t Kl[2][64 * 64];
    alignas(16) __shared__ half_t Vl[2][64 * 64];

    const int t = threadIdx.x, l = t & 63, wv = t >> 6;
    const int h2 = l >> 5, q32 = l & 31;
    const int bh = blockIdx.y, b = bh / 12, hh = bh % 12;
    const int q0 = blockIdx.x * 128 + wv * 32;

    // Q fragment (B-operand): col = q32, k = kd*16 + h2*8 + j; 1/8 scale folded in
    half8 qf[4];
    {
        const half_t* Qp = qkv + ((long)(b * 1024 + q0 + q32)) * 2304 + hh * 64 + h2 * 8;
#pragma unroll
        for (int kd = 0; kd < 4; ++kd) {
            half8 v = *(const half8*)(Qp + kd * 16);
#pragma unroll
            for (int j = 0; j < 8; ++j) v[j] = v[j] * (half_t)0.125f;
            qf[kd] = v;
        }
    }

    // staging bases (block-uniform)
    const half_t* Kg = qkv + (long)b * 1024 * 2304 + 768 + hh * 64;  // K[n][64]
    const half_t* Vg = Vt + (long)bh * 64 * 1024;                    // V^T[d][1024]

    // per-lane staging coords: 8 lanes per 128B row, chunk = l&7 (XOR-swizzled src)
    const int srow_lo = (l >> 3);         // row within 8-row group
    const int schunk = l & 7;

    auto STAGE = [&](int tile, int bf) {
#pragma unroll
        for (int c = 0; c < 2; ++c) {
            const int row = c * 32 + wv * 8 + srow_lo;
            const int sc_ = (schunk ^ (row & 7)) * 8;
            gload_lds16(Kg + (long)(tile * 64 + row) * 2304 + sc_,
                        &Kl[bf][(c * 32 + wv * 8) * 64]);
            gload_lds16(Vg + (long)row * 1024 + tile * 64 + sc_,
                        &Vl[bf][(c * 32 + wv * 8) * 64]);
        }
    };

    f32x16 o0 = {}, o1 = {};
    float m = -1e30f, ll = 0.f;

    STAGE(0, 0);
    __syncthreads();
    int bf = 0;

    for (int tt = 0; tt < 16; ++tt) {
        if (tt < 15) STAGE(tt + 1, bf ^ 1);

        // ---- S^T = K . Qs^T (K frags from LDS) ----
        f32x16 s0 = {}, s1 = {};
#pragma unroll
        for (int kd = 0; kd < 4; ++kd) {
            const int ch = ((kd * 2 + h2) ^ (q32 & 7)) * 8;
            half8 k0 = *(const half8*)&Kl[bf][q32 * 64 + ch];
            half8 k1 = *(const half8*)&Kl[bf][(32 + q32) * 64 + ch];
            s0 = __builtin_amdgcn_mfma_f32_32x32x16_f16(k0, qf[kd], s0, 0, 0, 0);
            s1 = __builtin_amdgcn_mfma_f32_32x32x16_f16(k1, qf[kd], s1, 0, 0, 0);
        }

        // ---- per-lane softmax (lane owns q = l&31; partner l^32 has other 16 kv) ----
        float mx = -1e30f;
#pragma unroll
        for (int i = 0; i < 16; ++i) mx = fmaxf(mx, s0[i]);
#pragma unroll
        for (int i = 0; i < 16; ++i) mx = fmaxf(mx, s1[i]);
        mx = fmaxf(mx, __shfl_xor(mx, 32));

        if (!__all(mx <= m + 8.f)) {          // defer-max (T13)
            const float mn = fmaxf(m, mx);
            const float al = __expf(m - mn);
            m = mn;
            ll *= al;
            o0 *= al;
            o1 *= al;
        }

        float sum = 0.f;
        unsigned P2w[8][2];
#pragma unroll
        for (int b8 = 0; b8 < 2; ++b8) {
            const f32x16 ss = b8 ? s1 : s0;
#pragma unroll
            for (int rr = 0; rr < 4; ++rr)
#pragma unroll
                for (int k = 0; k < 2; ++k) {
                    const float a = __expf(ss[rr * 4 + 2 * k] - m);
                    const float c = __expf(ss[rr * 4 + 2 * k + 1] - m);
                    sum += a + c;
                    P2w[b8 * 4 + rr][k] =
                        __builtin_bit_cast(unsigned, __builtin_amdgcn_cvt_pkrtz(a, c));
                }
        }
        sum += __shfl_xor(sum, 32);
        ll += sum;

        // exchange partner's complementary runs
        unsigned X[2][2][2];
#pragma unroll
        for (int b8 = 0; b8 < 2; ++b8)
#pragma unroll
            for (int j = 0; j < 2; ++j) {
                const unsigned z0 = h2 ? P2w[b8 * 4 + 2 * j][0] : P2w[b8 * 4 + 2 * j + 1][0];
                const unsigned z1 = h2 ? P2w[b8 * 4 + 2 * j][1] : P2w[b8 * 4 + 2 * j + 1][1];
                X[b8][j][0] = (unsigned)__shfl_xor((int)z0, 32);
                X[b8][j][1] = (unsigned)__shfl_xor((int)z1, 32);
            }

        // ---- O^T += V^T . P^T (V frags from LDS) ----
#pragma unroll
        for (int kc = 0; kc < 4; ++kc) {
            const int b8 = kc >> 1, j = kc & 1;
            const unsigned w0 = h2 ? X[b8][j][0] : P2w[b8 * 4 + 2 * j][0];
            const unsigned w1 = h2 ? X[b8][j][1] : P2w[b8 * 4 + 2 * j][1];
            const unsigned w2 = h2 ? P2w[b8 * 4 + 2 * j + 1][0] : X[b8][j][0];
            const unsigned w3 = h2 ? P2w[b8 * 4 + 2 * j + 1][1] : X[b8][j][1];
            uint4v uu = {w0, w1, w2, w3};
            const half8 pf = __builtin_bit_cast(half8, uu);
            const int ch = ((kc * 2 + h2) ^ (q32 & 7)) * 8;
            half8 v0 = *(const half8*)&Vl[bf][q32 * 64 + ch];
            half8 v1 = *(const half8*)&Vl[bf][(32 + q32) * 64 + ch];
            o0 = __builtin_amdgcn_mfma_f32_32x32x16_f16(v0, pf, o0, 0, 0, 0);
            o1 = __builtin_amdgcn_mfma_f32_32x32x16_f16(v1, pf, o1, 0, 0, 0);
        }

        __syncthreads();
        bf ^= 1;
    }

    // ---- epilogue: lane-local normalize + mask^2; d = db*32 + rq*8 + h2*4 + i ----
    const float hmv = head_mask[b * 12 + hh];
    const float sc = hmv * hmv / ll;
    half_t* Yp = Y + ((long)(b * 1024 + q0 + q32)) * 768 + hh * 64;
#pragma unroll
    for (int db = 0; db < 2; ++db) {
        const f32x16 oo = db ? o1 : o0;
#pragma unroll
        for (int rq = 0; rq < 4; ++rq) {
            half4_t pk;
#pragma unroll
            for (int i = 0; i < 4; ++i) pk[i] = (half_t)(oo[rq * 4 + i] * sc);
            *(half4_t*)(Yp + db * 32 + rq * 8 + h2 * 4) = pk;
        }
    }
}

// ---------------- launch ----------------
extern "C" void kernel_launch(void* const* d_in, const int* in_sizes, int n_in,
                              void* d_out, int out_size, void* d_ws, size_t ws_size,
                              hipStream_t stream) {
    const float* x   = (const float*)d_in[0];
    const float* hm  = (const float*)d_in[1];
    const float* q_w = (const float*)d_in[2];
    const float* q_b = (const float*)d_in[3];
    const float* k_w = (const float*)d_in[4];
    const float* k_b = (const float*)d_in[5];
    const float* v_w = (const float*)d_in[6];
    const float* v_b = (const float*)d_in[7];
    const float* p_w = (const float*)d_in[8];
    const float* p_b = (const float*)d_in[9];
    float* out = (float*)d_out;

    char* ws = (char*)d_ws;
    half_t* xh  = (half_t*)(ws);                    // 8192*768*2   = 12582912
    half_t* wc  = (half_t*)(ws + 12582912);         // 2304*768*2   = 3538944
    half_t* pwh = (half_t*)(ws + 16121856);         // 768*768*2    = 1179648
    float*  bc  = (float*)(ws + 17301504);          // 2304*4       = 9216
    half_t* qkv = (half_t*)(ws + 17310720);         // 8192*2304*2  = 37748736
    half_t* y   = (half_t*)(ws + 55059456);         // 8192*768*2   = 12582912
    half_t* Vt  = xh;                               // reuse xh (dead after QKV GEMM)

    cast_f32_f16<<<2048, 256, 0, stream>>>(x, xh, 8192 * 768);
    cast_f32_f16<<<576, 256, 0, stream>>>(q_w, wc, 768 * 768);
    cast_f32_f16<<<576, 256, 0, stream>>>(k_w, wc + 768 * 768, 768 * 768);
    cast_f32_f16<<<576, 256, 0, stream>>>(v_w, wc + 2 * 768 * 768, 768 * 768);
    cast_f32_f16<<<576, 256, 0, stream>>>(p_w, pwh, 768 * 768);
    concat_bias<<<9, 256, 0, stream>>>(q_b, k_b, v_b, bc);

    gemm_bt<half_t><<<dim3(64, 18), 256, 0, stream>>>(xh, wc, bc, qkv, 8192, 2304, 768);
    transpose_v<<<dim3(16, 96), 256, 0, stream>>>(qkv, Vt);
    attn3_kernel<<<dim3(8, 96), 256, 0, stream>>>(qkv, Vt, hm, y);
    gemm_bt<float><<<dim3(64, 6), 256, 0, stream>>>(y, pwh, p_b, out, 8192, 768, 768);
}